// Round 1
// baseline (505.731 us; speedup 1.0000x reference)
//
#include <hip/hip_runtime.h>

// Problem constants (B,H,S,D) = (8,8,1024,64), fp32 everywhere.
#define SEQ 1024
#define HD  64
#define BH  64          // B*H
#define PROJ_F4_PER (BH * SEQ * (HD / 4))   // 1,048,576 float4 per proj cache
#define ATTN_F4     (BH * SEQ * (SEQ / 4))  // 16,777,216 float4 total

// ---------------------------------------------------------------------------
// Proj caches: out[b,h,s,:] = (s==wr) ? new[b,h,0,:] : in[b,h, s+shift, :]
// One float4 per thread, covering q,k,v in one grid (which = idx >> 20).
// ---------------------------------------------------------------------------
__global__ __launch_bounds__(256) void proj_kernel(
    const float4* __restrict__ qc, const float4* __restrict__ kc,
    const float4* __restrict__ vc,
    const float4* __restrict__ qn, const float4* __restrict__ kn,
    const float4* __restrict__ vn,
    float4* __restrict__ oq, float4* __restrict__ ok, float4* __restrict__ ov,
    const int* __restrict__ cslp)
{
    const int csl   = *cslp;
    const int shift = (csl >= SEQ - 1) ? 1 : 0;
    const int wr    = shift ? (SEQ - 1) : csl;

    int idx = blockIdx.x * blockDim.x + threadIdx.x;   // < 3 * PROJ_F4_PER
    int which = idx >> 20;                              // 0,1,2 -> q,k,v
    int r     = idx & (PROJ_F4_PER - 1);
    int d4    = r & 15;                                 // float4 within head dim
    int s     = (r >> 4) & (SEQ - 1);
    int bh    = r >> 14;

    const float4* in; const float4* nw; float4* out;
    if      (which == 0) { in = qc; nw = qn; out = oq; }
    else if (which == 1) { in = kc; nw = kn; out = ok; }
    else                 { in = vc; nw = vn; out = ov; }

    float4 val;
    if (s == wr) {
        val = nw[bh * (HD / 4) + d4];
    } else {
        int ss = s + shift;           // s != wr, so when shift: s < SEQ-1 -> ss <= SEQ-1
        val = in[(bh * SEQ + ss) * (HD / 4) + d4];
    }
    out[r] = val;
}

// ---------------------------------------------------------------------------
// Attn cache: out[r,c] = (c==wr) ? k_t[b,h,r,0]
//                      : (r==wr) ? q_t[b,h,0,c]
//                      : in[b,h, r + 2*shift (clamped), c + 2*shift (clamped)]
// One float4 STORE per thread; source reads are scalar dwords (misaligned by
// +2 floats in the shift path) but consecutive lanes coalesce fully.
// ---------------------------------------------------------------------------
__global__ __launch_bounds__(256) void attn_kernel(
    const float* __restrict__ a,
    const float* __restrict__ qt,
    const float* __restrict__ kt,
    float*       __restrict__ out,
    const int*   __restrict__ cslp)
{
    const int csl   = *cslp;
    const int shift = (csl >= SEQ - 1) ? 1 : 0;
    const int wr    = shift ? (SEQ - 1) : csl;

    int idx = blockIdx.x * blockDim.x + threadIdx.x;    // float4 index, < ATTN_F4
    int c0  = (idx & (SEQ / 4 - 1)) << 2;               // starting column
    int rr  = (idx >> 8) & (SEQ - 1);                   // row
    int bh  = idx >> 18;                                // (b*H + h)

    float v[4];
    if (rr == wr) {
        const float* qrow = qt + bh * SEQ;
        #pragma unroll
        for (int j = 0; j < 4; ++j) {
            int c = c0 + j;
            v[j] = (c == wr) ? kt[bh * SEQ + wr] : qrow[c];
        }
    } else {
        int srcR = shift ? min(rr + 2, SEQ - 1) : rr;
        const float* arow = a + (bh * SEQ + srcR) * SEQ;
        #pragma unroll
        for (int j = 0; j < 4; ++j) {
            int c = c0 + j;
            if (c == wr) {
                v[j] = kt[bh * SEQ + rr];
            } else {
                int srcC = shift ? min(c + 2, SEQ - 1) : c;
                v[j] = arow[srcC];
            }
        }
    }
    reinterpret_cast<float4*>(out)[idx] = make_float4(v[0], v[1], v[2], v[3]);
}

extern "C" void kernel_launch(void* const* d_in, const int* in_sizes, int n_in,
                              void* d_out, int out_size, void* d_ws, size_t ws_size,
                              hipStream_t stream)
{
    const float* q_cache = (const float*)d_in[0];
    const float* k_cache = (const float*)d_in[1];
    const float* v_cache = (const float*)d_in[2];
    const float* a_cache = (const float*)d_in[3];
    const float* q_new   = (const float*)d_in[4];
    const float* k_new   = (const float*)d_in[5];
    const float* v_new   = (const float*)d_in[6];
    const float* q_t     = (const float*)d_in[7];
    const float* k_t     = (const float*)d_in[8];
    const int*   cslp    = (const int*)d_in[9];

    const int PROJ_ELEMS = BH * SEQ * HD;          // 4,194,304 per cache
    float* out_q = (float*)d_out;
    float* out_k = out_q + PROJ_ELEMS;
    float* out_v = out_k + PROJ_ELEMS;
    float* out_a = out_v + PROJ_ELEMS;

    // proj: 3 caches * 1,048,576 float4 / 256 threads = 12288 blocks
    proj_kernel<<<3 * PROJ_F4_PER / 256, 256, 0, stream>>>(
        (const float4*)q_cache, (const float4*)k_cache, (const float4*)v_cache,
        (const float4*)q_new,   (const float4*)k_new,   (const float4*)v_new,
        (float4*)out_q, (float4*)out_k, (float4*)out_v, cslp);

    // attn: 16,777,216 float4 / 256 threads = 65536 blocks
    attn_kernel<<<ATTN_F4 / 256, 256, 0, stream>>>(
        a_cache, q_t, k_t, out_a, cslp);
}